// Round 1
// baseline (39200.687 us; speedup 1.0000x reference)
//
#include <hip/hip_runtime.h>
#include <math.h>

#define B 64
#define T 512
#define II 512
#define H 512

__device__ __forceinline__ float sigmoidf_(float x){ return 1.0f/(1.0f + __expf(-x)); }

__global__ void zero_ws(float* p, int n){
  int i = blockIdx.x*blockDim.x + threadIdx.x;
  for (; i < n; i += gridDim.x*blockDim.x) p[i] = 0.0f;
}

// One timestep for BOTH directions. Grid: (128, 2) blocks of 256 threads.
// blockIdx.x: qtile = x & 31 (16 hidden cols each), btile = x >> 5 (16 batch rows each)
//   (qtile in LOW bits so the 4 btile-twins that read the same W rows land on the
//    same XCD under round-robin blockIdx->XCD mapping)
// Each block computes gates for its 16 hcols x 4 gate types (64 gate cols) x 16 rows,
// then does the LSTM elementwise update locally.
__global__ __launch_bounds__(256) void lstm_step(
    const float* __restrict__ xs,
    const float* __restrict__ Wih_f, const float* __restrict__ Whh_f,
    const float* __restrict__ bih_f, const float* __restrict__ bhh_f,
    const float* __restrict__ Wih_b, const float* __restrict__ Whh_b,
    const float* __restrict__ bih_b, const float* __restrict__ bhh_b,
    const float* __restrict__ h_in, float* __restrict__ h_out,
    float* __restrict__ c_st, float* __restrict__ out, int s)
{
  const int dir = blockIdx.y;
  const int t = dir ? (T-1-s) : s;
  const int qtile = blockIdx.x & 31;
  const int btile = blockIdx.x >> 5;
  const int q0 = qtile * 16;
  const int b0 = btile * 16;

  const float* __restrict__ Wih = dir ? Wih_b : Wih_f;
  const float* __restrict__ Whh = dir ? Whh_b : Whh_f;
  const float* __restrict__ bih = dir ? bih_b : bih_f;
  const float* __restrict__ bhh = dir ? bhh_b : bhh_f;

  const int tid = threadIdx.x;
  const int bg = tid >> 5;        // 8 groups of 2 batch rows
  const int cg = tid & 31;        // 32 groups of 2 gate cols
  const int r0 = b0 + bg*2;       // first of this thread's 2 batch rows
  const int c_ = cg*2;            // local col in [0,64), even
  // local col -> global gate col: c = gt*16 + hq  (gt in [0,4), hq in [0,16))
  const int gt0 = c_ >> 4;
  const int hq0 = c_ & 15;
  const int jc0 = gt0*H + q0 + hq0;   // c_+1 stays in same gate group (c_ even)
  const int jc1 = jc0 + 1;

  float acc00 = 0.f, acc01 = 0.f, acc10 = 0.f, acc11 = 0.f;

  // ---- x phase: gates += x_t @ Wih^T  (K = II) ----
  {
    const float4* a0 = (const float4*)(xs + ((size_t)(r0+0)*T + t)*II);
    const float4* a1 = (const float4*)(xs + ((size_t)(r0+1)*T + t)*II);
    const float4* w0 = (const float4*)(Wih + (size_t)jc0*II);
    const float4* w1 = (const float4*)(Wih + (size_t)jc1*II);
    #pragma unroll 8
    for (int k = 0; k < II/4; ++k){
      float4 x0 = a0[k], x1 = a1[k], v0 = w0[k], v1 = w1[k];
      acc00 += x0.x*v0.x + x0.y*v0.y + x0.z*v0.z + x0.w*v0.w;
      acc01 += x0.x*v1.x + x0.y*v1.y + x0.z*v1.z + x0.w*v1.w;
      acc10 += x1.x*v0.x + x1.y*v0.y + x1.z*v0.z + x1.w*v0.w;
      acc11 += x1.x*v1.x + x1.y*v1.y + x1.z*v1.z + x1.w*v1.w;
    }
  }
  // ---- h phase: gates += h_{t-1} @ Whh^T  (K = H) ----
  {
    const float4* a0 = (const float4*)(h_in + ((size_t)dir*B + r0+0)*H);
    const float4* a1 = (const float4*)(h_in + ((size_t)dir*B + r0+1)*H);
    const float4* w0 = (const float4*)(Whh + (size_t)jc0*H);
    const float4* w1 = (const float4*)(Whh + (size_t)jc1*H);
    #pragma unroll 8
    for (int k = 0; k < H/4; ++k){
      float4 x0 = a0[k], x1 = a1[k], v0 = w0[k], v1 = w1[k];
      acc00 += x0.x*v0.x + x0.y*v0.y + x0.z*v0.z + x0.w*v0.w;
      acc01 += x0.x*v1.x + x0.y*v1.y + x0.z*v1.z + x0.w*v1.w;
      acc10 += x1.x*v0.x + x1.y*v0.y + x1.z*v0.z + x1.w*v0.w;
      acc11 += x1.x*v1.x + x1.y*v1.y + x1.z*v1.z + x1.w*v1.w;
    }
  }

  const float bias0 = bih[jc0] + bhh[jc0];
  const float bias1 = bih[jc1] + bhh[jc1];

  __shared__ float g_lds[16][64];
  g_lds[bg*2+0][c_+0] = acc00 + bias0;
  g_lds[bg*2+0][c_+1] = acc01 + bias1;
  g_lds[bg*2+1][c_+0] = acc10 + bias0;
  g_lds[bg*2+1][c_+1] = acc11 + bias1;
  __syncthreads();

  // ---- elementwise LSTM update: 256 threads, one (b, hcol) each ----
  const int lb = tid >> 4;        // 0..15 local batch row
  const int hq = tid & 15;        // 0..15 local hidden col
  const int b  = b0 + lb;
  const int j  = q0 + hq;
  const float gi = g_lds[lb][ 0 + hq];
  const float gf = g_lds[lb][16 + hq];
  const float gg = g_lds[lb][32 + hq];
  const float go = g_lds[lb][48 + hq];

  const size_t sidx = ((size_t)dir*B + b)*H + j;
  const float cold = c_st[sidx];
  const float fi = sigmoidf_(gi);
  const float ff = sigmoidf_(gf);
  const float fg = tanhf(gg);
  const float fo = sigmoidf_(go);
  const float cn = ff*cold + fi*fg;
  const float hn = fo * tanhf(cn);
  c_st[sidx]  = cn;
  h_out[sidx] = hn;
  out[((size_t)b*T + t)*(2*H) + (size_t)dir*H + j] = hn;
}

extern "C" void kernel_launch(void* const* d_in, const int* in_sizes, int n_in,
                              void* d_out, int out_size, void* d_ws, size_t ws_size,
                              hipStream_t stream)
{
  const float* xs    = (const float*)d_in[0];
  const float* Wih_f = (const float*)d_in[1];
  const float* Whh_f = (const float*)d_in[2];
  const float* bih_f = (const float*)d_in[3];
  const float* bhh_f = (const float*)d_in[4];
  const float* Wih_b = (const float*)d_in[5];
  const float* Whh_b = (const float*)d_in[6];
  const float* bih_b = (const float*)d_in[7];
  const float* bhh_b = (const float*)d_in[8];
  float* out = (float*)d_out;
  float* ws  = (float*)d_ws;

  float* hA = ws;                    // [2][B][H]
  float* hB = ws + 2*B*H;            // [2][B][H]
  float* cS = ws + 4*B*H;            // [2][B][H]

  zero_ws<<<96, 256, 0, stream>>>(ws, 6*B*H);

  for (int s = 0; s < T; ++s){
    const float* hin = (s & 1) ? hB : hA;
    float*      hout = (s & 1) ? hA : hB;
    lstm_step<<<dim3(128, 2), 256, 0, stream>>>(
        xs, Wih_f, Whh_f, bih_f, bhh_f,
        Wih_b, Whh_b, bih_b, bhh_b,
        hin, hout, cS, out, s);
  }
}

// Round 2
// 29108.652 us; speedup vs baseline: 1.3467x; 1.3467x over previous
//
#include <hip/hip_runtime.h>
#include <math.h>

#define B 64
#define T 512
#define II 512
#define H 512
#define NBLK 256

typedef float f32x4 __attribute__((ext_vector_type(4)));
typedef short s16x8 __attribute__((ext_vector_type(8)));

__device__ __forceinline__ unsigned short f2b(float f){
  union { float f; unsigned u; } v; v.f = f;
  unsigned r = v.u + 0x7fffu + ((v.u >> 16) & 1u);
  return (unsigned short)(r >> 16);
}

__global__ void init_ws(unsigned* bar, unsigned short* hbufs, int nush){
  int i = blockIdx.x*blockDim.x + threadIdx.x;
  if (i < 2) bar[i] = 0u;
  for (int k = i; k < nush; k += gridDim.x*blockDim.x) hbufs[k] = 0;
}

// Persistent bidirectional LSTM. 256 blocks x 256 threads, 1 block/CU (132KB LDS).
// Block: dir (bx>>7), btile ((bx>>5)&3 -> 16 batch rows), qtile (bx&31 -> 16 hidden cols).
// 4 waves: wave w computes gate-type w's 16x16 tile via 32x mfma_f32_16x16x32_bf16.
// Weights (64 gate rows x K=1024) stay in LDS (bf16, XOR-swizzled) across all 512 steps.
// c-state lives in registers. One device-scope grid barrier per step.
__global__ __launch_bounds__(256, 1) void lstm_persistent(
    const float* __restrict__ xs,
    const float* __restrict__ Wih_f, const float* __restrict__ Whh_f,
    const float* __restrict__ bih_f, const float* __restrict__ bhh_f,
    const float* __restrict__ Wih_b, const float* __restrict__ Whh_b,
    const float* __restrict__ bih_b, const float* __restrict__ bhh_b,
    float* __restrict__ out,
    unsigned* __restrict__ bar,
    unsigned short* __restrict__ hbuf0, unsigned short* __restrict__ hbuf1)
{
  __shared__ unsigned short Wlds[4*16*1024];   // 128 KB bf16, swizzled
  __shared__ float g_lds[4][16][16];           // gates staging (4 KB)
  __shared__ float bias_s[64];

  const int tid = threadIdx.x;
  const int bx = blockIdx.x;
  const int dir   = bx >> 7;
  const int qtile = bx & 31;
  const int btile = (bx >> 5) & 3;
  const int q0 = qtile * 16;
  const int b0 = btile * 16;

  const float* __restrict__ Wih = dir ? Wih_b : Wih_f;
  const float* __restrict__ Whh = dir ? Whh_b : Whh_f;
  const float* __restrict__ bih = dir ? bih_b : bih_f;
  const float* __restrict__ bhh = dir ? bhh_b : bhh_f;

  // ---- load weight slice into LDS (bf16, XOR-swizzled for conflict-free B-frag reads) ----
  for (int it = 0; it < 32; ++it){
    int idx = it * 256 + tid;          // 8192 chunks of 8 elems
    int c64 = idx >> 7;                // 0..63 local gate row
    int k   = (idx & 127) * 8;         // 0..1016
    int cg  = (c64 >> 4) * H + q0 + (c64 & 15);   // global gate row
    const float* src = (k < II) ? (Wih + (size_t)cg * II + k)
                                : (Whh + (size_t)cg * H + (k - II));
    float4 lo = *(const float4*)src;
    float4 hi = *(const float4*)(src + 4);
    s16x8 v;
    v[0]=(short)f2b(lo.x); v[1]=(short)f2b(lo.y); v[2]=(short)f2b(lo.z); v[3]=(short)f2b(lo.w);
    v[4]=(short)f2b(hi.x); v[5]=(short)f2b(hi.y); v[6]=(short)f2b(hi.z); v[7]=(short)f2b(hi.w);
    unsigned byte = ((unsigned)c64 * 2048u + (unsigned)k * 2u) ^ (((unsigned)(c64 & 7)) << 4);
    *(s16x8*)((char*)Wlds + byte) = v;
  }
  if (tid < 64){
    int g = tid >> 4, jj = tid & 15;
    int cg = g * H + q0 + jj;
    bias_s[tid] = bih[cg] + bhh[cg];
  }
  __syncthreads();

  const int w = tid >> 6;                 // wave = gate type
  const int l = tid & 63;
  const int arow = b0 + (l & 15);         // A-frag batch row
  const int kgrp = (l >> 4) * 8;          // k offset within K=32 window
  const int c64w = (w << 4) | (l & 15);   // B-frag local gate row
  const unsigned swz = ((unsigned)(c64w & 7)) << 4;
  const unsigned wbase = (unsigned)c64w * 2048u;

  const int eb = tid >> 4;                // elementwise: local batch row
  const int ej = tid & 15;                //             local hidden col
  float c_reg = 0.f;

  const size_t hbase = (size_t)dir * B * H;

  #pragma unroll 1
  for (int s = 0; s < T; ++s){
    const int t = dir ? (T - 1 - s) : s;
    const unsigned short* __restrict__ hin  = (s & 1) ? hbuf1 : hbuf0;
    unsigned short* __restrict__       hout = (s & 1) ? hbuf0 : hbuf1;

    f32x4 acc0 = {0.f,0.f,0.f,0.f}, acc1 = {0.f,0.f,0.f,0.f};
    const float* xrow = xs + ((size_t)arow * T + t) * II + kgrp;
    const unsigned short* hrow = hin + hbase + (size_t)arow * H + kgrp;

    #pragma unroll
    for (int ks = 0; ks < 16; ++ks){      // x half: K = 0..511
      float4 lo = *(const float4*)(xrow + ks*32);
      float4 hi = *(const float4*)(xrow + ks*32 + 4);
      s16x8 a;
      a[0]=(short)f2b(lo.x); a[1]=(short)f2b(lo.y); a[2]=(short)f2b(lo.z); a[3]=(short)f2b(lo.w);
      a[4]=(short)f2b(hi.x); a[5]=(short)f2b(hi.y); a[6]=(short)f2b(hi.z); a[7]=(short)f2b(hi.w);
      unsigned byte = (wbase + (unsigned)(ks*32 + kgrp) * 2u) ^ swz;
      s16x8 bfr = *(const s16x8*)((const char*)Wlds + byte);
      acc0 = __builtin_amdgcn_mfma_f32_16x16x32_bf16(a, bfr, acc0, 0, 0, 0);
    }
    #pragma unroll
    for (int ks = 0; ks < 16; ++ks){      // h half: K = 512..1023
      s16x8 a = *(const s16x8*)(hrow + ks*32);
      unsigned byte = (wbase + (unsigned)(II + ks*32 + kgrp) * 2u) ^ swz;
      s16x8 bfr = *(const s16x8*)((const char*)Wlds + byte);
      acc1 = __builtin_amdgcn_mfma_f32_16x16x32_bf16(a, bfr, acc1, 0, 0, 0);
    }

    #pragma unroll
    for (int r = 0; r < 4; ++r){
      int bl = (l >> 4) * 4 + r;          // C/D: row=(lane>>4)*4+reg, col=lane&15
      g_lds[w][bl][l & 15] = acc0[r] + acc1[r];
    }
    __syncthreads();

    {
      float gi = g_lds[0][eb][ej] + bias_s[ej];
      float gf = g_lds[1][eb][ej] + bias_s[16 + ej];
      float gg = g_lds[2][eb][ej] + bias_s[32 + ej];
      float go = g_lds[3][eb][ej] + bias_s[48 + ej];
      float si = 1.f/(1.f + __expf(-gi));
      float sf = 1.f/(1.f + __expf(-gf));
      float tg = tanhf(gg);
      float so = 1.f/(1.f + __expf(-go));
      c_reg = sf * c_reg + si * tg;
      float hn = so * tanhf(c_reg);
      int b = b0 + eb, j = q0 + ej;
      out[((size_t)b * T + t) * (2*H) + (size_t)dir * H + j] = hn;
      hout[hbase + (size_t)b * H + j] = f2b(hn);
    }

    __syncthreads();                      // all g_lds reads + global writes issued
    if (tid == 0){
      __threadfence();                    // release our h writes device-wide
      unsigned g = __hip_atomic_load(&bar[1], __ATOMIC_RELAXED, __HIP_MEMORY_SCOPE_AGENT);
      unsigned arrived = __hip_atomic_fetch_add(&bar[0], 1u, __ATOMIC_ACQ_REL, __HIP_MEMORY_SCOPE_AGENT);
      if (arrived == NBLK - 1){
        __hip_atomic_store(&bar[0], 0u, __ATOMIC_RELAXED, __HIP_MEMORY_SCOPE_AGENT);
        __hip_atomic_fetch_add(&bar[1], 1u, __ATOMIC_RELEASE, __HIP_MEMORY_SCOPE_AGENT);
      } else {
        while (__hip_atomic_load(&bar[1], __ATOMIC_ACQUIRE, __HIP_MEMORY_SCOPE_AGENT) == g){
          __builtin_amdgcn_s_sleep(2);
        }
      }
    }
    __syncthreads();
    __threadfence();                      // acquire side: refresh caches for next h reads
  }
}

extern "C" void kernel_launch(void* const* d_in, const int* in_sizes, int n_in,
                              void* d_out, int out_size, void* d_ws, size_t ws_size,
                              hipStream_t stream)
{
  const float* xs    = (const float*)d_in[0];
  const float* Wih_f = (const float*)d_in[1];
  const float* Whh_f = (const float*)d_in[2];
  const float* bih_f = (const float*)d_in[3];
  const float* bhh_f = (const float*)d_in[4];
  const float* Wih_b = (const float*)d_in[5];
  const float* Whh_b = (const float*)d_in[6];
  const float* bih_b = (const float*)d_in[7];
  const float* bhh_b = (const float*)d_in[8];
  float* out = (float*)d_out;

  char* ws = (char*)d_ws;
  unsigned* bar = (unsigned*)ws;                               // 2 x u32
  unsigned short* hbuf0 = (unsigned short*)(ws + 256);         // [2][B][H] bf16
  unsigned short* hbuf1 = (unsigned short*)(ws + 256 + 2*B*H*2);

  init_ws<<<128, 256, 0, stream>>>(bar, hbuf0, 2*2*B*H);
  lstm_persistent<<<NBLK, 256, 0, stream>>>(
      xs, Wih_f, Whh_f, bih_f, bhh_f,
      Wih_b, Whh_b, bih_b, bhh_b,
      out, bar, hbuf0, hbuf1);
}

// Round 3
// 10396.302 us; speedup vs baseline: 3.7706x; 2.7999x over previous
//
#include <hip/hip_runtime.h>
#include <math.h>

#define B 64
#define T 512
#define II 512
#define H 512
#define NBLK 256

typedef float f32x4 __attribute__((ext_vector_type(4)));
typedef short s16x8 __attribute__((ext_vector_type(8)));

__device__ __forceinline__ unsigned short f2b(float f){
  union { float f; unsigned u; } v; v.f = f;
  unsigned r = v.u + 0x7fffu + ((v.u >> 16) & 1u);
  return (unsigned short)(r >> 16);
}

__global__ void init_ws(unsigned* p, int n){
  int i = blockIdx.x*blockDim.x + threadIdx.x;
  for (; i < n; i += gridDim.x*blockDim.x) p[i] = 0u;
}

// Persistent bidirectional LSTM. 256 blocks x 256 threads, 1 block/CU (135KB LDS).
// Barrier v2: per-block flag lines (release store, no RMW) -> block0 scans all 256
// flags with relaxed agent loads -> block0 release-stores 8 epoch copies ->
// blocks poll their epoch copy relaxed -> one acquire fence per wave per step.
__global__ __launch_bounds__(256, 1) void lstm_persistent(
    const float* __restrict__ xs,
    const float* __restrict__ Wih_f, const float* __restrict__ Whh_f,
    const float* __restrict__ bih_f, const float* __restrict__ bhh_f,
    const float* __restrict__ Wih_b, const float* __restrict__ Whh_b,
    const float* __restrict__ bih_b, const float* __restrict__ bhh_b,
    float* __restrict__ out,
    unsigned* __restrict__ flags,    // [256] cachelines, stride 32 u32
    unsigned* __restrict__ epochs,   // [8] cachelines, stride 32 u32
    unsigned short* __restrict__ hbuf0, unsigned short* __restrict__ hbuf1)
{
  __shared__ unsigned short Wlds[4*16*1024];   // 128 KB bf16, swizzled
  __shared__ float g_lds[4][16][16];
  __shared__ float bias_s[64];

  const int tid = threadIdx.x;
  const int bx = blockIdx.x;
  const int dir   = bx >> 7;
  const int qtile = bx & 31;
  const int btile = (bx >> 5) & 3;
  const int q0 = qtile * 16;
  const int b0 = btile * 16;

  const float* __restrict__ Wih = dir ? Wih_b : Wih_f;
  const float* __restrict__ Whh = dir ? Whh_b : Whh_f;
  const float* __restrict__ bih = dir ? bih_b : bih_f;
  const float* __restrict__ bhh = dir ? bhh_b : bhh_f;

  // ---- stage weights into LDS (bf16, XOR-swizzled) ----
  for (int it = 0; it < 32; ++it){
    int idx = it * 256 + tid;
    int c64 = idx >> 7;
    int k   = (idx & 127) * 8;
    int cg  = (c64 >> 4) * H + q0 + (c64 & 15);
    const float* src = (k < II) ? (Wih + (size_t)cg * II + k)
                                : (Whh + (size_t)cg * H + (k - II));
    float4 lo = *(const float4*)src;
    float4 hi = *(const float4*)(src + 4);
    s16x8 v;
    v[0]=(short)f2b(lo.x); v[1]=(short)f2b(lo.y); v[2]=(short)f2b(lo.z); v[3]=(short)f2b(lo.w);
    v[4]=(short)f2b(hi.x); v[5]=(short)f2b(hi.y); v[6]=(short)f2b(hi.z); v[7]=(short)f2b(hi.w);
    unsigned byte = ((unsigned)c64 * 2048u + (unsigned)k * 2u) ^ (((unsigned)(c64 & 7)) << 4);
    *(s16x8*)((char*)Wlds + byte) = v;
  }
  if (tid < 64){
    int g = tid >> 4, jj = tid & 15;
    int cg = g * H + q0 + jj;
    bias_s[tid] = bih[cg] + bhh[cg];
  }
  __syncthreads();

  const int w = tid >> 6;
  const int l = tid & 63;
  const int arow = b0 + (l & 15);
  const int kgrp = (l >> 4) * 8;
  const int c64w = (w << 4) | (l & 15);
  const unsigned swz = ((unsigned)(c64w & 7)) << 4;
  const unsigned wbase = (unsigned)c64w * 2048u;

  const int eb = tid >> 4;
  const int ej = tid & 15;
  float c_reg = 0.f;

  const size_t hbase = (size_t)dir * B * H;

  // prefetch x A-fragments for step 0 into registers
  s16x8 a_x[16];
  {
    const int t0 = dir ? (T-1) : 0;
    const float* xrow = xs + ((size_t)arow * T + t0) * II + kgrp;
    #pragma unroll
    for (int ks = 0; ks < 16; ++ks){
      float4 lo = *(const float4*)(xrow + ks*32);
      float4 hi = *(const float4*)(xrow + ks*32 + 4);
      s16x8 a;
      a[0]=(short)f2b(lo.x); a[1]=(short)f2b(lo.y); a[2]=(short)f2b(lo.z); a[3]=(short)f2b(lo.w);
      a[4]=(short)f2b(hi.x); a[5]=(short)f2b(hi.y); a[6]=(short)f2b(hi.z); a[7]=(short)f2b(hi.w);
      a_x[ks] = a;
    }
  }

  #pragma unroll 1
  for (int s = 0; s < T; ++s){
    const int t = dir ? (T - 1 - s) : s;
    const unsigned short* __restrict__ hin  = (s & 1) ? hbuf1 : hbuf0;
    unsigned short* __restrict__       hout = (s & 1) ? hbuf0 : hbuf1;

    f32x4 acc0 = {0.f,0.f,0.f,0.f}, acc1 = {0.f,0.f,0.f,0.f};

    #pragma unroll
    for (int ks = 0; ks < 16; ++ks){      // x half from prefetched regs
      unsigned byte = (wbase + (unsigned)(ks*32 + kgrp) * 2u) ^ swz;
      s16x8 bfr = *(const s16x8*)((const char*)Wlds + byte);
      acc0 = __builtin_amdgcn_mfma_f32_16x16x32_bf16(a_x[ks], bfr, acc0, 0, 0, 0);
    }
    {
      const unsigned short* hrow = hin + hbase + (size_t)arow * H + kgrp;
      #pragma unroll
      for (int ks = 0; ks < 16; ++ks){    // h half
        s16x8 a = *(const s16x8*)(hrow + ks*32);
        unsigned byte = (wbase + (unsigned)(II + ks*32 + kgrp) * 2u) ^ swz;
        s16x8 bfr = *(const s16x8*)((const char*)Wlds + byte);
        acc1 = __builtin_amdgcn_mfma_f32_16x16x32_bf16(a, bfr, acc1, 0, 0, 0);
      }
    }

    #pragma unroll
    for (int r = 0; r < 4; ++r){
      int bl = (l >> 4) * 4 + r;
      g_lds[w][bl][l & 15] = acc0[r] + acc1[r];
    }
    __syncthreads();

    {
      float gi = g_lds[0][eb][ej] + bias_s[ej];
      float gf = g_lds[1][eb][ej] + bias_s[16 + ej];
      float gg = g_lds[2][eb][ej] + bias_s[32 + ej];
      float go = g_lds[3][eb][ej] + bias_s[48 + ej];
      float si = 1.f/(1.f + __expf(-gi));
      float sf = 1.f/(1.f + __expf(-gf));
      float tg = tanhf(gg);
      float so = 1.f/(1.f + __expf(-go));
      c_reg = sf * c_reg + si * tg;
      float hn = so * tanhf(c_reg);
      int b = b0 + eb, j = q0 + ej;
      out[((size_t)b * T + t) * (2*H) + (size_t)dir * H + j] = hn;
      hout[hbase + (size_t)b * H + j] = f2b(hn);
    }

    __syncthreads();   // all waves' hout stores vmcnt-drained before release

    // ---- arrival: one release store to our own flag line (emits one wbl2) ----
    if (tid == 0)
      __hip_atomic_store(&flags[(unsigned)bx << 5], (unsigned)(s+1),
                         __ATOMIC_RELEASE, __HIP_MEMORY_SCOPE_AGENT);

    // ---- overlap: prefetch next step's x A-fragments during the wait ----
    if (s + 1 < T){
      const int tn = dir ? (T - 2 - s) : (s + 1);
      const float* xrow = xs + ((size_t)arow * T + tn) * II + kgrp;
      #pragma unroll
      for (int ks = 0; ks < 16; ++ks){
        float4 lo = *(const float4*)(xrow + ks*32);
        float4 hi = *(const float4*)(xrow + ks*32 + 4);
        s16x8 a;
        a[0]=(short)f2b(lo.x); a[1]=(short)f2b(lo.y); a[2]=(short)f2b(lo.z); a[3]=(short)f2b(lo.w);
        a[4]=(short)f2b(hi.x); a[5]=(short)f2b(hi.y); a[6]=(short)f2b(hi.z); a[7]=(short)f2b(hi.w);
        a_x[ks] = a;
      }
    }

    // ---- block 0 scans all flags (relaxed, per-address, no invalidates) ----
    if (bx == 0){
      int done;
      do {
        unsigned v = __hip_atomic_load(&flags[(unsigned)tid << 5],
                                       __ATOMIC_RELAXED, __HIP_MEMORY_SCOPE_AGENT);
        done = (v > (unsigned)s);
      } while (!__syncthreads_and(done));
      if (tid < 8)
        __hip_atomic_store(&epochs[(unsigned)tid << 5], (unsigned)(s+1),
                           __ATOMIC_RELEASE, __HIP_MEMORY_SCOPE_AGENT);
    }

    // ---- wait for epoch flip (relaxed poll on our copy) ----
    if (tid == 0){
      const unsigned eidx = ((unsigned)bx & 7) << 5;
      while (__hip_atomic_load(&epochs[eidx], __ATOMIC_RELAXED,
                               __HIP_MEMORY_SCOPE_AGENT) <= (unsigned)s){
        __builtin_amdgcn_s_sleep(2);
      }
    }
    __syncthreads();
    __builtin_amdgcn_fence(__ATOMIC_ACQUIRE, "agent");  // one inv per wave, post-flip
  }
}

extern "C" void kernel_launch(void* const* d_in, const int* in_sizes, int n_in,
                              void* d_out, int out_size, void* d_ws, size_t ws_size,
                              hipStream_t stream)
{
  const float* xs    = (const float*)d_in[0];
  const float* Wih_f = (const float*)d_in[1];
  const float* Whh_f = (const float*)d_in[2];
  const float* bih_f = (const float*)d_in[3];
  const float* bhh_f = (const float*)d_in[4];
  const float* Wih_b = (const float*)d_in[5];
  const float* Whh_b = (const float*)d_in[6];
  const float* bih_b = (const float*)d_in[7];
  const float* bhh_b = (const float*)d_in[8];
  float* out = (float*)d_out;

  char* ws = (char*)d_ws;
  unsigned* flags  = (unsigned*)ws;                      // 256 lines * 128B = 32 KB
  unsigned* epochs = (unsigned*)(ws + 32768);            // 8 lines * 128B = 1 KB
  unsigned short* hbuf0 = (unsigned short*)(ws + 36864); // [2][B][H] bf16 = 128 KB
  unsigned short* hbuf1 = (unsigned short*)(ws + 36864 + 2*B*H*2);

  const int init_u32 = (36864 + 2*(2*B*H*2)) / 4;
  init_ws<<<128, 256, 0, stream>>>((unsigned*)ws, init_u32);

  lstm_persistent<<<NBLK, 256, 0, stream>>>(
      xs, Wih_f, Whh_f, bih_f, bhh_f,
      Wih_b, Whh_b, bih_b, bhh_b,
      out, flags, epochs, hbuf0, hbuf1);
}

// Round 4
// 3177.089 us; speedup vs baseline: 12.3386x; 3.2723x over previous
//
#include <hip/hip_runtime.h>
#include <math.h>

#define B 64
#define T 512
#define II 512
#define H 512
#define NBLK 256

typedef float f32x4 __attribute__((ext_vector_type(4)));
typedef short s16x8 __attribute__((ext_vector_type(8)));
typedef unsigned long long u64;

__device__ __forceinline__ unsigned short f2b(float f){
  union { float f; unsigned u; } v; v.f = f;
  unsigned r = v.u + 0x7fffu + ((v.u >> 16) & 1u);
  return (unsigned short)(r >> 16);
}

__global__ void init_ws(unsigned* p, int n){
  int i = blockIdx.x*blockDim.x + threadIdx.x;
  for (; i < n; i += gridDim.x*blockDim.x) p[i] = 0u;
}

// Persistent bidirectional LSTM. 256 blocks x 256 threads, 1 block/CU (~148KB LDS).
// Sync v3 (fence-free): h moves through the coherence point via relaxed agent-scope
// atomics (no wbl2/inv ever). 8 independent 32-block group barriers (group =
// dir x btile), leaderless: 32 threads poll the group's 32 flag lines directly.
// Weights stay in LDS (bf16, XOR-swizzled) all 512 steps; c-state in registers.
__global__ __launch_bounds__(256, 1) void lstm_persistent(
    const float* __restrict__ xs,
    const float* __restrict__ Wih_f, const float* __restrict__ Whh_f,
    const float* __restrict__ bih_f, const float* __restrict__ bhh_f,
    const float* __restrict__ Wih_b, const float* __restrict__ Whh_b,
    const float* __restrict__ bih_b, const float* __restrict__ bhh_b,
    float* __restrict__ out,
    unsigned* __restrict__ flags,    // [256] cachelines (32 u32 stride)
    unsigned short* __restrict__ hbuf0, unsigned short* __restrict__ hbuf1)
{
  __shared__ unsigned short Wlds[4*16*1024];   // 128 KB bf16, swizzled
  __shared__ unsigned short Hlds[16*512];      // 16 KB bf16, swizzled
  __shared__ float g_lds[4][16][16];
  __shared__ float bias_s[64];

  const int tid = threadIdx.x;
  const int bx = blockIdx.x;
  const int dir   = bx >> 7;
  const int qtile = bx & 31;
  const int btile = (bx >> 5) & 3;
  const int q0 = qtile * 16;
  const int b0 = btile * 16;

  const float* __restrict__ Wih = dir ? Wih_b : Wih_f;
  const float* __restrict__ Whh = dir ? Whh_b : Whh_f;
  const float* __restrict__ bih = dir ? bih_b : bih_f;
  const float* __restrict__ bhh = dir ? bhh_b : bhh_f;

  // ---- stage weights into LDS (bf16, XOR-swizzled) ----
  for (int it = 0; it < 32; ++it){
    int idx = it * 256 + tid;
    int c64 = idx >> 7;
    int k   = (idx & 127) * 8;
    int cg  = (c64 >> 4) * H + q0 + (c64 & 15);
    const float* src = (k < II) ? (Wih + (size_t)cg * II + k)
                                : (Whh + (size_t)cg * H + (k - II));
    float4 lo = *(const float4*)src;
    float4 hi = *(const float4*)(src + 4);
    s16x8 v;
    v[0]=(short)f2b(lo.x); v[1]=(short)f2b(lo.y); v[2]=(short)f2b(lo.z); v[3]=(short)f2b(lo.w);
    v[4]=(short)f2b(hi.x); v[5]=(short)f2b(hi.y); v[6]=(short)f2b(hi.z); v[7]=(short)f2b(hi.w);
    unsigned byte = ((unsigned)c64 * 2048u + (unsigned)k * 2u) ^ (((unsigned)(c64 & 7)) << 4);
    *(s16x8*)((char*)Wlds + byte) = v;
  }
  if (tid < 64){
    int g = tid >> 4, jj = tid & 15;
    int cg = g * H + q0 + jj;
    bias_s[tid] = bih[cg] + bhh[cg];
  }
  __syncthreads();

  const int w = tid >> 6;                 // wave = gate type
  const int l = tid & 63;
  const int arow = b0 + (l & 15);
  const int kgrp = (l >> 4) * 8;
  const int c64w = (w << 4) | (l & 15);
  const unsigned swz = ((unsigned)(c64w & 7)) << 4;
  const unsigned wbase = (unsigned)c64w * 2048u;
  const unsigned hrowb = ((unsigned)(l & 15)) * 1024u;
  const unsigned hswz  = ((unsigned)(l & 7)) << 4;

  const int eb = tid >> 4;                // elementwise batch row
  const int ej = tid & 15;                // elementwise hidden col
  const int hr = tid >> 4;                // h-staging row
  const int hc = (tid & 15) * 32;         // h-staging col base (32 bf16 = 64B)
  float c_reg = 0.f;

  const size_t hbase = (size_t)dir * B * H;
  const unsigned gflag0 = (unsigned)(bx & ~31);   // group's first flag line
  const unsigned myflag = (unsigned)bx << 5;

  // prefetch x A-fragments for step 0
  s16x8 a_x[16];
  {
    const int t0 = dir ? (T-1) : 0;
    const float* xrow = xs + ((size_t)arow * T + t0) * II + kgrp;
    #pragma unroll
    for (int ks = 0; ks < 16; ++ks){
      float4 lo = *(const float4*)(xrow + ks*32);
      float4 hi = *(const float4*)(xrow + ks*32 + 4);
      s16x8 a;
      a[0]=(short)f2b(lo.x); a[1]=(short)f2b(lo.y); a[2]=(short)f2b(lo.z); a[3]=(short)f2b(lo.w);
      a[4]=(short)f2b(hi.x); a[5]=(short)f2b(hi.y); a[6]=(short)f2b(hi.z); a[7]=(short)f2b(hi.w);
      a_x[ks] = a;
    }
  }

  #pragma unroll 1
  for (int s = 0; s < T; ++s){
    const int t = dir ? (T - 1 - s) : s;
    const unsigned short* __restrict__ hin  = (s & 1) ? hbuf1 : hbuf0;
    unsigned short* __restrict__       hout = (s & 1) ? hbuf0 : hbuf1;

    // ---- A: issue h loads through the coherence point (relaxed agent atomics) ----
    u64 hv[8];
    {
      const u64* hsrc = (const u64*)(hin + hbase + (size_t)(b0 + hr) * H + hc);
      #pragma unroll
      for (int i = 0; i < 8; ++i)
        hv[i] = __hip_atomic_load(hsrc + i, __ATOMIC_RELAXED, __HIP_MEMORY_SCOPE_AGENT);
    }

    // ---- B: x-half MFMAs on prefetched regs (hides h-load latency) ----
    f32x4 acc0 = {0.f,0.f,0.f,0.f}, acc1 = {0.f,0.f,0.f,0.f};
    #pragma unroll
    for (int ks = 0; ks < 16; ++ks){
      unsigned byte = (wbase + (unsigned)(ks*32 + kgrp) * 2u) ^ swz;
      s16x8 bfr = *(const s16x8*)((const char*)Wlds + byte);
      acc0 = __builtin_amdgcn_mfma_f32_16x16x32_bf16(a_x[ks], bfr, acc0, 0, 0, 0);
    }

    // ---- C: stage h into LDS (XOR-swizzled), sync ----
    #pragma unroll
    for (int i = 0; i < 8; ++i){
      unsigned byte = ((unsigned)hr * 1024u + (unsigned)(hc + i*4) * 2u)
                    ^ (((unsigned)(hr & 7)) << 4);
      *(u64*)((char*)Hlds + byte) = hv[i];
    }
    __syncthreads();

    // ---- D: h-half MFMAs from LDS ----
    #pragma unroll
    for (int ks = 0; ks < 16; ++ks){
      unsigned hbyte = (hrowb + (unsigned)(ks*32 + kgrp) * 2u) ^ hswz;
      s16x8 a = *(const s16x8*)((const char*)Hlds + hbyte);
      unsigned byte = (wbase + (unsigned)(II + ks*32 + kgrp) * 2u) ^ swz;
      s16x8 bfr = *(const s16x8*)((const char*)Wlds + byte);
      acc1 = __builtin_amdgcn_mfma_f32_16x16x32_bf16(a, bfr, acc1, 0, 0, 0);
    }

    // ---- E: gates to LDS, sync ----
    #pragma unroll
    for (int r = 0; r < 4; ++r){
      int bl = (l >> 4) * 4 + r;
      g_lds[w][bl][l & 15] = acc0[r] + acc1[r];
    }
    __syncthreads();

    // ---- F: elementwise LSTM update; publish h via relaxed agent stores ----
    float hn;
    {
      float gi = g_lds[0][eb][ej] + bias_s[ej];
      float gf = g_lds[1][eb][ej] + bias_s[16 + ej];
      float gg = g_lds[2][eb][ej] + bias_s[32 + ej];
      float go = g_lds[3][eb][ej] + bias_s[48 + ej];
      float si = 1.f/(1.f + __expf(-gi));
      float sf = 1.f/(1.f + __expf(-gf));
      float tg = tanhf(gg);
      float so = 1.f/(1.f + __expf(-go));
      c_reg = sf * c_reg + si * tg;
      hn = so * tanhf(c_reg);
      unsigned hb = (unsigned)f2b(hn);
      unsigned pv = (unsigned)__shfl_xor((int)hb, 1, 64);
      if (!(tid & 1)){
        unsigned idx = (unsigned)((hbase + (size_t)(b0 + eb) * H + (q0 + ej)) >> 1);
        __hip_atomic_store((unsigned*)hout + idx, hb | (pv << 16),
                           __ATOMIC_RELAXED, __HIP_MEMORY_SCOPE_AGENT);
      }
    }

    // ---- G: drain (syncthreads waits vmcnt), then flag (one relaxed store) ----
    __syncthreads();
    if (s + 1 < T && tid == 0)
      __hip_atomic_store(&flags[myflag], (unsigned)(s+1),
                         __ATOMIC_RELAXED, __HIP_MEMORY_SCOPE_AGENT);

    // ---- H: out store + next x prefetch (in flight during the poll) ----
    out[((size_t)(b0+eb) * T + t) * (2*H) + (size_t)dir * H + (q0 + ej)] = hn;
    if (s + 1 < T){
      const int tn = dir ? (T - 2 - s) : (s + 1);
      const float* xrow = xs + ((size_t)arow * T + tn) * II + kgrp;
      #pragma unroll
      for (int ks = 0; ks < 16; ++ks){
        float4 lo = *(const float4*)(xrow + ks*32);
        float4 hi = *(const float4*)(xrow + ks*32 + 4);
        s16x8 a;
        a[0]=(short)f2b(lo.x); a[1]=(short)f2b(lo.y); a[2]=(short)f2b(lo.z); a[3]=(short)f2b(lo.w);
        a[4]=(short)f2b(hi.x); a[5]=(short)f2b(hi.y); a[6]=(short)f2b(hi.z); a[7]=(short)f2b(hi.w);
        a_x[ks] = a;
      }

      // ---- I: leaderless group barrier — 32 threads poll 32 flag lines ----
      for (;;){
        int done = 1;
        if (tid < 32)
          done = (__hip_atomic_load(&flags[(gflag0 + (unsigned)tid) << 5],
                                    __ATOMIC_RELAXED, __HIP_MEMORY_SCOPE_AGENT)
                  > (unsigned)s);
        if (__syncthreads_and(done)) break;
        __builtin_amdgcn_s_sleep(1);
      }
    }
  }
}

extern "C" void kernel_launch(void* const* d_in, const int* in_sizes, int n_in,
                              void* d_out, int out_size, void* d_ws, size_t ws_size,
                              hipStream_t stream)
{
  const float* xs    = (const float*)d_in[0];
  const float* Wih_f = (const float*)d_in[1];
  const float* Whh_f = (const float*)d_in[2];
  const float* bih_f = (const float*)d_in[3];
  const float* bhh_f = (const float*)d_in[4];
  const float* Wih_b = (const float*)d_in[5];
  const float* Whh_b = (const float*)d_in[6];
  const float* bih_b = (const float*)d_in[7];
  const float* bhh_b = (const float*)d_in[8];
  float* out = (float*)d_out;

  char* ws = (char*)d_ws;
  unsigned* flags = (unsigned*)ws;                       // 256 lines * 128B = 32 KB
  unsigned short* hbuf0 = (unsigned short*)(ws + 32768); // [2][B][H] bf16 = 128 KB
  unsigned short* hbuf1 = (unsigned short*)(ws + 32768 + 2*B*H*2);

  const int init_u32 = (32768 + 2*(2*B*H*2)) / 4;
  init_ws<<<128, 256, 0, stream>>>((unsigned*)ws, init_u32);

  lstm_persistent<<<NBLK, 256, 0, stream>>>(
      xs, Wih_f, Whh_f, bih_f, bhh_f,
      Wih_b, Whh_b, bih_b, bhh_b,
      out, flags, hbuf0, hbuf1);
}